// Round 1
// baseline (366.535 us; speedup 1.0000x reference)
//
#include <hip/hip_runtime.h>
#include <hip/hip_bf16.h>

// Problem constants (from reference)
#define DFEAT   64
#define NREL    8
#define KDIM    512     // DFEAT * NREL
#define DOUT    64
#define NBASES  4

// ---------------------------------------------------------------------------
// K1: Wflat[(i*8+r)*64 + o] = sum_b w_rel[r,b] * w_bases[b,i,o]
// 512*64 = 32768 elements, one thread each.
// ---------------------------------------------------------------------------
__global__ __launch_bounds__(256) void weight_kernel(
    const float* __restrict__ w_rel,    // [NREL][NBASES]
    const float* __restrict__ w_bases,  // [NBASES][DFEAT][DOUT]
    float* __restrict__ wflat)          // [KDIM][DOUT]
{
    int idx = blockIdx.x * 256 + threadIdx.x;   // 0..32767
    int o = idx & 63;
    int k = idx >> 6;       // i*8 + r
    int i = k >> 3;
    int r = k & 7;
    float s = 0.f;
#pragma unroll
    for (int b = 0; b < NBASES; ++b)
        s += w_rel[r * NBASES + b] * w_bases[(b * DFEAT + i) * DOUT + o];
    wflat[idx] = s;
}

// ---------------------------------------------------------------------------
// K2: Y[n][o] = sum_k Xflat[n][k] * Wflat[k][o]
// [N,512] @ [512,64]. Block tile: 64 nodes x 64 outs, BK=32.
// 256 threads, each computes a 4x4 register tile (4 nodes x 4 outs).
// ---------------------------------------------------------------------------
#define BN   64
#define BK   32
#define XPAD 4   // keeps 16B alignment of rows (stride 68 floats = 272B)

__global__ __launch_bounds__(256) void transform_kernel(
    const float* __restrict__ x,    // [n_nodes][KDIM]
    const float* __restrict__ w,    // [KDIM][DOUT]
    float* __restrict__ y,          // [n_nodes][DOUT]
    int n_nodes)
{
    __shared__ float xs[BK][BN + XPAD];  // transposed x tile
    __shared__ float ws[BK][DOUT];       // w tile

    const int tid = threadIdx.x;
    const int node0 = blockIdx.x * BN;

    const int tn = tid >> 4;   // 0..15 node group (4 nodes)
    const int to = tid & 15;   // 0..15 out group  (4 outs)

    // x staging: thread loads 2 float4 of one node row
    const int ln = tid >> 2;        // 0..63 node within tile
    const int lk = (tid & 3) * 8;   // 0,8,16,24

    int xrow = node0 + ln;
    if (xrow >= n_nodes) xrow = n_nodes - 1;   // clamp: safe load, store guarded
    const float* xg = x + (size_t)xrow * KDIM;

    float acc[4][4];
#pragma unroll
    for (int a = 0; a < 4; ++a)
#pragma unroll
        for (int b = 0; b < 4; ++b) acc[a][b] = 0.f;

    for (int kb = 0; kb < KDIM; kb += BK) {
        float4 xa = *(const float4*)(xg + kb + lk);
        float4 xb = *(const float4*)(xg + kb + lk + 4);
        float4 wa = *(const float4*)(w + kb * DOUT + tid * 4);
        float4 wb = *(const float4*)(w + kb * DOUT + 1024 + tid * 4);

        __syncthreads();   // protect previous iteration's LDS reads
        xs[lk + 0][ln] = xa.x; xs[lk + 1][ln] = xa.y;
        xs[lk + 2][ln] = xa.z; xs[lk + 3][ln] = xa.w;
        xs[lk + 4][ln] = xb.x; xs[lk + 5][ln] = xb.y;
        xs[lk + 6][ln] = xb.z; xs[lk + 7][ln] = xb.w;
        *(float4*)(&ws[0][0] + tid * 4) = wa;
        *(float4*)(&ws[0][0] + 1024 + tid * 4) = wb;
        __syncthreads();

#pragma unroll
        for (int kk = 0; kk < BK; ++kk) {
            float4 xv = *(const float4*)&xs[kk][tn * 4];
            float4 wv = *(const float4*)&ws[kk][to * 4];
            float xr[4] = {xv.x, xv.y, xv.z, xv.w};
            float wr[4] = {wv.x, wv.y, wv.z, wv.w};
#pragma unroll
            for (int a = 0; a < 4; ++a)
#pragma unroll
                for (int b = 0; b < 4; ++b)
                    acc[a][b] += xr[a] * wr[b];
        }
    }

#pragma unroll
    for (int a = 0; a < 4; ++a) {
        int node = node0 + tn * 4 + a;
        if (node < n_nodes) {
            float4 v = make_float4(acc[a][0], acc[a][1], acc[a][2], acc[a][3]);
            *(float4*)(y + (size_t)node * DOUT + to * 4) = v;
        }
    }
}

// ---------------------------------------------------------------------------
// K3: out[dst] += w_e * Y[src] over edges. One 64-lane wave per edge,
// lane = feature. Coalesced gather of Y row + coalesced fp32 atomics.
// ---------------------------------------------------------------------------
__global__ __launch_bounds__(256) void scatter_kernel(
    const int* __restrict__ esrc,
    const int* __restrict__ edst,
    const float* __restrict__ ew,
    const float* __restrict__ y,
    float* __restrict__ out,
    int n_edges)
{
    int e = blockIdx.x * 4 + (threadIdx.x >> 6);
    int o = threadIdx.x & 63;
    if (e < n_edges) {
        int s = esrc[e];
        int d = edst[e];
        float w = ew[e];
        atomicAdd(&out[(size_t)d * DOUT + o], w * y[(size_t)s * DOUT + o]);
    }
}

extern "C" void kernel_launch(void* const* d_in, const int* in_sizes, int n_in,
                              void* d_out, int out_size, void* d_ws, size_t ws_size,
                              hipStream_t stream) {
    const float* x       = (const float*)d_in[0];
    const int*   esrc    = (const int*)d_in[1];
    const int*   edst    = (const int*)d_in[2];
    const float* ew      = (const float*)d_in[3];
    const float* w_bases = (const float*)d_in[4];
    const float* w_rel   = (const float*)d_in[5];
    float* out = (float*)d_out;

    const int n_nodes = in_sizes[0] / KDIM;
    const int n_edges = in_sizes[1];

    // Workspace layout: Y [n_nodes*64] then Wflat [512*64]
    float* y     = (float*)d_ws;
    float* wflat = y + (size_t)n_nodes * DOUT;

    // out is poisoned 0xAA before every launch — zero it (atomic accumulate target)
    hipMemsetAsync(d_out, 0, (size_t)out_size * sizeof(float), stream);

    weight_kernel<<<(KDIM * DOUT) / 256, 256, 0, stream>>>(w_rel, w_bases, wflat);

    transform_kernel<<<(n_nodes + BN - 1) / BN, 256, 0, stream>>>(x, wflat, y, n_nodes);

    int sblocks = (n_edges + 3) / 4;   // 4 edges per 256-thread block
    scatter_kernel<<<sblocks, 256, 0, stream>>>(esrc, edst, ew, y, out, n_edges);
}